// Round 1
// baseline (253.161 us; speedup 1.0000x reference)
//
#include <hip/hip_runtime.h>
#include <stdint.h>

#define B_   32
#define CIN  256
#define COUT 512
#define A_   256
#define HW_  4096
#define NT   64
#define TILES 8

typedef short  short8  __attribute__((ext_vector_type(8)));
typedef float  float4_ __attribute__((ext_vector_type(4)));

__device__ __forceinline__ unsigned f2bf(float f) {
    unsigned u = __float_as_uint(f);
    u += 0x7FFFu + ((u >> 16) & 1u);   // RNE to bf16
    return u >> 16;
}
__device__ __forceinline__ float bf2f(unsigned h) {
    return __uint_as_float(h << 16);
}

// Kernel 0 (grid 64):
//  blocks 0..31  : zero P/T, ggbx[b][a] = g@Wg.T + bg + bx
//  blocks 32..63 : WxR fragment-linear repack of Wx (bf16)
//    entry e = ((w8*8+kk)*4+ai)*64 + lane  holds Wx[a=w8*64+ai*16+(lane&15)]
//                                               [k=kk*32+(lane>>4)*8 .. +7]
__global__ __launch_bounds__(256) void prep_kernel(
    const float* __restrict__ g, const float* __restrict__ Wg,
    const float* __restrict__ bg, const float* __restrict__ Wx,
    const float* __restrict__ bx,
    uint4* __restrict__ WxR, float* __restrict__ ggbx,
    float* __restrict__ P, float* __restrict__ T)
{
    int t = threadIdx.x;
    if (blockIdx.x >= 32) {
        int e = (blockIdx.x - 32) * 256 + t;
        int lane = e & 63, ai = (e >> 6) & 3, kk = (e >> 8) & 7, w = e >> 11;
        int a  = w * 64 + ai * 16 + (lane & 15);
        int kb = kk * 32 + (lane >> 4) * 8;
        const float4* s = (const float4*)(Wx + (size_t)a * 256 + kb);
        float4 u0 = s[0], u1 = s[1];
        uint4 pk;
        pk.x = f2bf(u0.x) | (f2bf(u0.y) << 16);
        pk.y = f2bf(u0.z) | (f2bf(u0.w) << 16);
        pk.z = f2bf(u1.x) | (f2bf(u1.y) << 16);
        pk.w = f2bf(u1.z) | (f2bf(u1.w) << 16);
        WxR[e] = pk;
        return;
    }
    int b = blockIdx.x;
    int i = b * 256 + t;
    P[i] = 0.f; T[i] = 0.f;

    __shared__ float gl[COUT];
    gl[t]       = g[b * COUT + t];
    gl[t + 256] = g[b * COUT + 256 + t];
    __syncthreads();

    float acc0 = bg[t] + bx[t], acc1 = 0.f;    // a = t, dual chain for ILP
    const float4* wr = (const float4*)(Wg + (size_t)t * COUT);
    #pragma unroll 8
    for (int co = 0; co < COUT / 4; co += 2) {
        float4 wv0 = wr[co],     gv0 = *(const float4*)&gl[co * 4];
        float4 wv1 = wr[co + 1], gv1 = *(const float4*)&gl[co * 4 + 4];
        acc0 += wv0.x * gv0.x + wv0.y * gv0.y + wv0.z * gv0.z + wv0.w * gv0.w;
        acc1 += wv1.x * gv1.x + wv1.y * gv1.y + wv1.z * gv1.z + wv1.w * gv1.w;
    }
    ggbx[b * 256 + t] = acc0 + acc1;
}

// Kernel 1: grid 256 (1 block/CU), 512 threads (8 waves). Each block owns
// (b, tg) = 8 consecutive n-tiles of 64. Pipeline per tile:
//   issue loads(i+1) -> GEMM/epilogue/PT on buf[i&1] -> convert+write buf[(i+1)&1]
// Wave w owns a in [w*32, w*32+32); its WxR slice (16 short8) is register-
// resident for the whole block, so the K-loop is pure LDS+MFMA.
__global__ __launch_bounds__(512, 2) void attn_main(
    const float* __restrict__ x, const char* __restrict__ WxR,
    const float* __restrict__ ggbx, const float* __restrict__ Wf,
    const float* __restrict__ bfs,
    float* __restrict__ P, float* __restrict__ T, float* __restrict__ raw)
{
    // xT[buf][n][chunk]: chunk q (8 c as bf16x8) XOR-swizzled by n&31
    __shared__ unsigned int xT[2][NT * 128];    // 2 x 32 KB
    __shared__ float att_part[8][NT];
    __shared__ float raw_l[NT];

    int bid = blockIdx.x;
    int b = bid >> 3, tg = bid & 7;
    int t = threadIdx.x, w = t >> 6, lane = t & 63;
    int quad = lane >> 4, l15 = lane & 15;

    const float* xb = x + (size_t)b * CIN * HW_ + tg * (TILES * NT);

    // ---- persistent B fragments: wave w -> a in [w*32, w*32+32) ----
    short8 bfp[16];
    {
        const char* wsl = WxR + (w >> 1) * 32768 + (w & 1) * 2048 + lane * 16;
        #pragma unroll
        for (int kk = 0; kk < 8; kk++) {
            bfp[kk * 2]     = *(const short8*)(wsl + kk * 4096);
            bfp[kk * 2 + 1] = *(const short8*)(wsl + kk * 4096 + 1024);
        }
    }

    float ga[2], wfv[2];
    #pragma unroll
    for (int ai = 0; ai < 2; ai++) {
        int a = w * 32 + ai * 16 + l15;
        ga[ai]  = ggbx[b * 256 + a];
        wfv[ai] = Wf[a];
    }

    // staging geometry: wave w stages c in [w*32, w*32+32), 8 rows/thread
    int n4 = l15 * 4;
    int cb = w * 32 + quad * 8;
    int qc = cb >> 3;                            // = w*4 + quad
    const float* xrow = xb + (size_t)cb * HW_ + n4;

    // ---- prologue: tile 0 ----
    float4_ v[8];
    #pragma unroll
    for (int j = 0; j < 8; j++)
        v[j] = *(const float4_*)(xrow + (size_t)j * HW_);
    #pragma unroll
    for (int r = 0; r < 4; r++) {
        uint4 pk;
        pk.x = f2bf(v[0][r]) | (f2bf(v[1][r]) << 16);
        pk.y = f2bf(v[2][r]) | (f2bf(v[3][r]) << 16);
        pk.z = f2bf(v[4][r]) | (f2bf(v[5][r]) << 16);
        pk.w = f2bf(v[6][r]) | (f2bf(v[7][r]) << 16);
        int n = n4 + r;
        *(uint4*)&xT[0][n * 128 + ((qc ^ (n & 31)) << 2)] = pk;
    }

    float pp[4] = {0.f, 0.f, 0.f, 0.f};
    float tt[4] = {0.f, 0.f, 0.f, 0.f};
    int qpt   = (t & 63) >> 1;                   // P/T: logical chunk (8 c)
    int half  = (t & 1) * 8;                     // which 4 c of the chunk
    int nbase = w * 8;                           // P/T: 8 n per wave

    __syncthreads();

    #pragma unroll
    for (int it = 0; it < TILES; it++) {
        const unsigned int* xl = xT[it & 1];

        // issue next tile's loads; land under GEMM+epilogue+P/T
        if (it < TILES - 1) {
            const float* xn = xrow + (it + 1) * NT;
            #pragma unroll
            for (int j = 0; j < 8; j++)
                v[j] = *(const float4_*)(xn + (size_t)j * HW_);
        }

        // ---- K loop: pure LDS + MFMA (B is register-resident) ----
        float4_ acc[4][2];
        #pragma unroll
        for (int mi = 0; mi < 4; mi++) {
            acc[mi][0] = (float4_){0.f, 0.f, 0.f, 0.f};
            acc[mi][1] = (float4_){0.f, 0.f, 0.f, 0.f};
        }
        short8 afA[4], afB[4];
        auto LDA = [&](short8* af, int k0) {
            int qk = (k0 >> 3) + quad;
            #pragma unroll
            for (int mi = 0; mi < 4; mi++) {
                int n = mi * 16 + l15;
                af[mi] = *(const short8*)&xl[n * 128 + ((qk ^ (n & 31)) << 2)];
            }
        };
        auto MM = [&](short8* af, int ks) {
            #pragma unroll
            for (int mi = 0; mi < 4; mi++) {
                acc[mi][0] = __builtin_amdgcn_mfma_f32_16x16x32_bf16(
                    af[mi], bfp[ks * 2],     acc[mi][0], 0, 0, 0);
                acc[mi][1] = __builtin_amdgcn_mfma_f32_16x16x32_bf16(
                    af[mi], bfp[ks * 2 + 1], acc[mi][1], 0, 0, 0);
            }
        };

        LDA(afA, 0);   LDA(afB, 32);
        MM(afA, 0);    LDA(afA, 64);
        MM(afB, 1);    LDA(afB, 96);
        MM(afA, 2);    LDA(afA, 128);
        MM(afB, 3);    LDA(afB, 160);
        MM(afA, 4);    LDA(afA, 192);
        MM(afB, 5);    LDA(afB, 224);
        MM(afA, 6);
        MM(afB, 7);

        // ---- epilogue: relu(D + gg + bx) * Wf, reduce over a ----
        #pragma unroll
        for (int mi = 0; mi < 4; mi++) {
            float p[4] = {0.f, 0.f, 0.f, 0.f};
            #pragma unroll
            for (int ai = 0; ai < 2; ai++) {
                #pragma unroll
                for (int r = 0; r < 4; r++) {
                    float vv = fmaxf(acc[mi][ai][r] + ga[ai], 0.f);
                    p[r] = fmaf(vv, wfv[ai], p[r]);
                }
            }
            #pragma unroll
            for (int r = 0; r < 4; r++) {
                #pragma unroll
                for (int off = 1; off < 16; off <<= 1)
                    p[r] += __shfl_xor(p[r], off, 16);
            }
            if (l15 == 0) {
                #pragma unroll
                for (int r = 0; r < 4; r++)
                    att_part[w][mi * 16 + quad * 4 + r] = p[r];
            }
        }
        __syncthreads();

        if (t < NT) {
            float rv = att_part[0][t] + att_part[1][t] + att_part[2][t] + att_part[3][t]
                     + att_part[4][t] + att_part[5][t] + att_part[6][t] + att_part[7][t]
                     + bfs[0];
            raw[b * HW_ + (tg * TILES + it) * NT + t] = rv;
            raw_l[t] = rv;
        }
        __syncthreads();

        // ---- P/T accumulate: thread owns 4 c over 8 n, across all tiles ----
        #pragma unroll
        for (int i = 0; i < 8; i++) {
            int n = nbase + i;
            uint2 u = *(const uint2*)((const char*)xl + n * 512 + ((qpt ^ (n & 31)) << 4) + half);
            float rv = raw_l[n];
            float x0 = bf2f(u.x & 0xFFFFu), x1 = bf2f(u.x >> 16);
            float x2 = bf2f(u.y & 0xFFFFu), x3 = bf2f(u.y >> 16);
            pp[0] = fmaf(x0, rv, pp[0]); tt[0] += x0;
            pp[1] = fmaf(x1, rv, pp[1]); tt[1] += x1;
            pp[2] = fmaf(x2, rv, pp[2]); tt[2] += x2;
            pp[3] = fmaf(x3, rv, pp[3]); tt[3] += x3;
        }

        // ---- convert + write next tile into the other buffer ----
        if (it < TILES - 1) {
            #pragma unroll
            for (int r = 0; r < 4; r++) {
                uint4 pk;
                pk.x = f2bf(v[0][r]) | (f2bf(v[1][r]) << 16);
                pk.y = f2bf(v[2][r]) | (f2bf(v[3][r]) << 16);
                pk.z = f2bf(v[4][r]) | (f2bf(v[5][r]) << 16);
                pk.w = f2bf(v[6][r]) | (f2bf(v[7][r]) << 16);
                int n = n4 + r;
                *(uint4*)&xT[(it + 1) & 1][n * 128 + ((qc ^ (n & 31)) << 2)] = pk;
            }
        }
        __syncthreads();
    }

    // ---- block-level P/T reduce (scratch = buf0; tile 7 read buf1) ----
    {
        float* red = (float*)xT;                 // [8 waves][512]: [0..255]=P, [256..511]=T
        float4_* pr = (float4_*)(red + w * 512);
        float4_* tr = (float4_*)(red + w * 512 + 256);
        pr[lane] = (float4_){pp[0], pp[1], pp[2], pp[3]};
        tr[lane] = (float4_){tt[0], tt[1], tt[2], tt[3]};
        __syncthreads();
        int sel = t >> 8, cc = t & 255;          // 256 thr P, 256 thr T
        float s = 0.f;
        #pragma unroll
        for (int g = 0; g < 8; g++)
            s += red[g * 512 + sel * 256 + cc];
        atomicAdd((sel ? T : P) + b * 256 + cc, s);
    }
}

// Kernel 2: per batch: min/sum over raw, write att output and pooled out
__global__ __launch_bounds__(256) void finalize_kernel(
    const float* __restrict__ raw, const float* __restrict__ P,
    const float* __restrict__ T, float* __restrict__ out)
{
    int b = blockIdx.x, t = threadIdx.x;
    const float* r = raw + (size_t)b * HW_;
    float v[16];
    float mn = 3.4e38f, sm = 0.f;
    #pragma unroll
    for (int i = 0; i < 16; i++) {
        v[i] = r[t + 256 * i];
        mn = fminf(mn, v[i]);
        sm += v[i];
    }
    #pragma unroll
    for (int off = 1; off < 64; off <<= 1) {
        mn = fminf(mn, __shfl_xor(mn, off, 64));
        sm += __shfl_xor(sm, off, 64);
    }
    __shared__ float smn[4], ssm[4];
    int w = t >> 6;
    if ((t & 63) == 0) { smn[w] = mn; ssm[w] = sm; }
    __syncthreads();
    mn = fminf(fminf(smn[0], smn[1]), fminf(smn[2], smn[3]));
    sm = (ssm[0] + ssm[1]) + (ssm[2] + ssm[3]);
    float S = sm - 4096.f * mn;                 // sum of (raw - min)
    float inv = 1.f / S;

    float* att = out + B_ * CIN + (size_t)b * HW_;
    #pragma unroll
    for (int i = 0; i < 16; i++) att[t + 256 * i] = (v[i] - mn) * inv;

    int ic = b * 256 + t;
    out[ic] = (P[ic] - mn * T[ic]) * inv;
}

extern "C" void kernel_launch(void* const* d_in, const int* in_sizes, int n_in,
                              void* d_out, int out_size, void* d_ws, size_t ws_size,
                              hipStream_t stream)
{
    const float* x   = (const float*)d_in[0];
    const float* g   = (const float*)d_in[1];
    const float* Wg  = (const float*)d_in[2];
    const float* bg  = (const float*)d_in[3];
    const float* Wx  = (const float*)d_in[4];
    const float* bx  = (const float*)d_in[5];
    const float* Wf  = (const float*)d_in[6];
    const float* bf  = (const float*)d_in[7];
    float* out = (float*)d_out;

    char* wsb = (char*)d_ws;
    uint4* WxR  = (uint4*)wsb;                            // 128 KB
    float* ggbx = (float*)(wsb + 131072);                 // 32 KB
    float* P    = ggbx + 8192;                            // 32 KB
    float* T    = P + 8192;                               // 32 KB
    float* raw  = T + 8192;                               // 512 KB

    prep_kernel<<<64, 256, 0, stream>>>(g, Wg, bg, Wx, bx, WxR, ggbx, P, T);
    attn_main<<<256, 512, 0, stream>>>(x, (const char*)WxR, ggbx, Wf, bf, P, T, raw);
    finalize_kernel<<<32, 256, 0, stream>>>(raw, P, T, out);
}

// Round 2
// 232.534 us; speedup vs baseline: 1.0887x; 1.0887x over previous
//
#include <hip/hip_runtime.h>
#include <stdint.h>

#define B_   32
#define CIN  256
#define COUT 512
#define A_   256
#define HW_  4096
#define NT   64
#define TILES 8

typedef short  short8  __attribute__((ext_vector_type(8)));
typedef float  float4_ __attribute__((ext_vector_type(4)));

__device__ __forceinline__ unsigned f2bf(float f) {
    unsigned u = __float_as_uint(f);
    u += 0x7FFFu + ((u >> 16) & 1u);   // RNE to bf16
    return u >> 16;
}
__device__ __forceinline__ float bf2f(unsigned h) {
    return __uint_as_float(h << 16);
}

// Kernel 0 (grid 64):
//  blocks 0..31  : zero P/T, ggbx[b][a] = g@Wg.T + bg + bx
//  blocks 32..63 : WxR fragment-linear repack of Wx (bf16)
//    entry e = ((w8*8+kk)*4+ai)*64 + lane  holds Wx[a=w8*64+ai*16+(lane&15)]
//                                               [k=kk*32+(lane>>4)*8 .. +7]
__global__ __launch_bounds__(256) void prep_kernel(
    const float* __restrict__ g, const float* __restrict__ Wg,
    const float* __restrict__ bg, const float* __restrict__ Wx,
    const float* __restrict__ bx,
    uint4* __restrict__ WxR, float* __restrict__ ggbx,
    float* __restrict__ P, float* __restrict__ T)
{
    int t = threadIdx.x;
    if (blockIdx.x >= 32) {
        int e = (blockIdx.x - 32) * 256 + t;
        int lane = e & 63, ai = (e >> 6) & 3, kk = (e >> 8) & 7, w = e >> 11;
        int a  = w * 64 + ai * 16 + (lane & 15);
        int kb = kk * 32 + (lane >> 4) * 8;
        const float4* s = (const float4*)(Wx + (size_t)a * 256 + kb);
        float4 u0 = s[0], u1 = s[1];
        uint4 pk;
        pk.x = f2bf(u0.x) | (f2bf(u0.y) << 16);
        pk.y = f2bf(u0.z) | (f2bf(u0.w) << 16);
        pk.z = f2bf(u1.x) | (f2bf(u1.y) << 16);
        pk.w = f2bf(u1.z) | (f2bf(u1.w) << 16);
        WxR[e] = pk;
        return;
    }
    int b = blockIdx.x;
    int i = b * 256 + t;
    P[i] = 0.f; T[i] = 0.f;

    __shared__ float gl[COUT];
    gl[t]       = g[b * COUT + t];
    gl[t + 256] = g[b * COUT + 256 + t];
    __syncthreads();

    float acc0 = bg[t] + bx[t], acc1 = 0.f;    // a = t, dual chain for ILP
    const float4* wr = (const float4*)(Wg + (size_t)t * COUT);
    #pragma unroll 8
    for (int co = 0; co < COUT / 4; co += 2) {
        float4 wv0 = wr[co],     gv0 = *(const float4*)&gl[co * 4];
        float4 wv1 = wr[co + 1], gv1 = *(const float4*)&gl[co * 4 + 4];
        acc0 += wv0.x * gv0.x + wv0.y * gv0.y + wv0.z * gv0.z + wv0.w * gv0.w;
        acc1 += wv1.x * gv1.x + wv1.y * gv1.y + wv1.z * gv1.z + wv1.w * gv1.w;
    }
    ggbx[b * 256 + t] = acc0 + acc1;
}

// Kernel 1: grid 256 (1 block/CU), 512 threads (8 waves). Each block owns
// (b, tg) = 8 consecutive n-tiles of 64. Pipeline per tile:
//   issue loads(i+1) -> GEMM/epilogue/PT on buf[i&1] -> convert+write buf[(i+1)&1]
// Wave w owns a in [w*32, w*32+32); its WxR slice (16 short8) is register-
// resident for the whole block, so the K-loop is pure LDS+MFMA.
// waves_per_eu(2,2): budget exactly 2 waves/SIMD -> 256 VGPR cap. Round-1's
// launch_bounds(512,2) let the allocator target 128 VGPR and spill bfp
// (+35 MB scratch writes, K-loop serialized on scratch reloads).
__global__ __launch_bounds__(512)
__attribute__((amdgpu_waves_per_eu(2, 2)))
void attn_main(
    const float* __restrict__ x, const char* __restrict__ WxR,
    const float* __restrict__ ggbx, const float* __restrict__ Wf,
    const float* __restrict__ bfs,
    float* __restrict__ P, float* __restrict__ T, float* __restrict__ raw)
{
    // xT[buf][n][chunk]: chunk q (8 c as bf16x8) XOR-swizzled by n&31
    __shared__ unsigned int xT[2][NT * 128];    // 2 x 32 KB
    __shared__ float att_part[8][NT];
    __shared__ float raw_l[NT];

    int bid = blockIdx.x;
    int b = bid >> 3, tg = bid & 7;
    int t = threadIdx.x, w = t >> 6, lane = t & 63;
    int quad = lane >> 4, l15 = lane & 15;

    const float* xb = x + (size_t)b * CIN * HW_ + tg * (TILES * NT);

    // ---- persistent B fragments: wave w -> a in [w*32, w*32+32) ----
    short8 bfp[16];
    {
        const char* wsl = WxR + (w >> 1) * 32768 + (w & 1) * 2048 + lane * 16;
        #pragma unroll
        for (int kk = 0; kk < 8; kk++) {
            bfp[kk * 2]     = *(const short8*)(wsl + kk * 4096);
            bfp[kk * 2 + 1] = *(const short8*)(wsl + kk * 4096 + 1024);
        }
    }

    float ga[2], wfv[2];
    #pragma unroll
    for (int ai = 0; ai < 2; ai++) {
        int a = w * 32 + ai * 16 + l15;
        ga[ai]  = ggbx[b * 256 + a];
        wfv[ai] = Wf[a];
    }

    // staging geometry: wave w stages c in [w*32, w*32+32), 8 rows/thread
    int n4 = l15 * 4;
    int cb = w * 32 + quad * 8;
    int qc = cb >> 3;                            // = w*4 + quad
    const float* xrow = xb + (size_t)cb * HW_ + n4;

    // ---- prologue: tile 0 ----
    float4_ v[8];
    #pragma unroll
    for (int j = 0; j < 8; j++)
        v[j] = *(const float4_*)(xrow + (size_t)j * HW_);
    #pragma unroll
    for (int r = 0; r < 4; r++) {
        uint4 pk;
        pk.x = f2bf(v[0][r]) | (f2bf(v[1][r]) << 16);
        pk.y = f2bf(v[2][r]) | (f2bf(v[3][r]) << 16);
        pk.z = f2bf(v[4][r]) | (f2bf(v[5][r]) << 16);
        pk.w = f2bf(v[6][r]) | (f2bf(v[7][r]) << 16);
        int n = n4 + r;
        *(uint4*)&xT[0][n * 128 + ((qc ^ (n & 31)) << 2)] = pk;
    }

    float pp[4] = {0.f, 0.f, 0.f, 0.f};
    float tt[4] = {0.f, 0.f, 0.f, 0.f};
    int qpt   = (t & 63) >> 1;                   // P/T: logical chunk (8 c)
    int half  = (t & 1) * 8;                     // which 4 c of the chunk
    int nbase = w * 8;                           // P/T: 8 n per wave

    __syncthreads();

    // unroll 1: full unroll let the scheduler rename v[] across tiles and
    // keep multiple tiles' loads in flight -> pressure blowup. LDS buffer
    // select (it&1) is an address computation, fine at runtime.
    #pragma unroll 1
    for (int it = 0; it < TILES; it++) {
        const unsigned int* xl = xT[it & 1];
        unsigned int* xw = xT[(it + 1) & 1];

        // issue next tile's loads; land under GEMM+epilogue+P/T
        if (it < TILES - 1) {
            const float* xn = xrow + (it + 1) * NT;
            #pragma unroll
            for (int j = 0; j < 8; j++)
                v[j] = *(const float4_*)(xn + (size_t)j * HW_);
        }

        // ---- K loop: pure LDS + MFMA (B is register-resident) ----
        float4_ acc[4][2];
        #pragma unroll
        for (int mi = 0; mi < 4; mi++) {
            acc[mi][0] = (float4_){0.f, 0.f, 0.f, 0.f};
            acc[mi][1] = (float4_){0.f, 0.f, 0.f, 0.f};
        }
        short8 afA[4], afB[4];
        auto LDA = [&](short8* af, int k0) {
            int qk = (k0 >> 3) + quad;
            #pragma unroll
            for (int mi = 0; mi < 4; mi++) {
                int n = mi * 16 + l15;
                af[mi] = *(const short8*)&xl[n * 128 + ((qk ^ (n & 31)) << 2)];
            }
        };
        auto MM = [&](short8* af, int ks) {
            #pragma unroll
            for (int mi = 0; mi < 4; mi++) {
                acc[mi][0] = __builtin_amdgcn_mfma_f32_16x16x32_bf16(
                    af[mi], bfp[ks * 2],     acc[mi][0], 0, 0, 0);
                acc[mi][1] = __builtin_amdgcn_mfma_f32_16x16x32_bf16(
                    af[mi], bfp[ks * 2 + 1], acc[mi][1], 0, 0, 0);
            }
        };

        LDA(afA, 0);   LDA(afB, 32);
        MM(afA, 0);    LDA(afA, 64);
        MM(afB, 1);    LDA(afB, 96);
        MM(afA, 2);    LDA(afA, 128);
        MM(afB, 3);    LDA(afB, 160);
        MM(afA, 4);    LDA(afA, 192);
        MM(afB, 5);    LDA(afB, 224);
        MM(afA, 6);
        MM(afB, 7);

        // ---- epilogue: relu(D + gg + bx) * Wf, reduce over a ----
        #pragma unroll
        for (int mi = 0; mi < 4; mi++) {
            float p[4] = {0.f, 0.f, 0.f, 0.f};
            #pragma unroll
            for (int ai = 0; ai < 2; ai++) {
                #pragma unroll
                for (int r = 0; r < 4; r++) {
                    float vv = fmaxf(acc[mi][ai][r] + ga[ai], 0.f);
                    p[r] = fmaf(vv, wfv[ai], p[r]);
                }
            }
            #pragma unroll
            for (int r = 0; r < 4; r++) {
                #pragma unroll
                for (int off = 1; off < 16; off <<= 1)
                    p[r] += __shfl_xor(p[r], off, 16);
            }
            if (l15 == 0) {
                #pragma unroll
                for (int r = 0; r < 4; r++)
                    att_part[w][mi * 16 + quad * 4 + r] = p[r];
            }
        }
        __syncthreads();

        if (t < NT) {
            float rv = att_part[0][t] + att_part[1][t] + att_part[2][t] + att_part[3][t]
                     + att_part[4][t] + att_part[5][t] + att_part[6][t] + att_part[7][t]
                     + bfs[0];
            raw[b * HW_ + (tg * TILES + it) * NT + t] = rv;
            raw_l[t] = rv;
        }
        __syncthreads();

        // ---- P/T accumulate: thread owns 4 c over 8 n, across all tiles ----
        #pragma unroll
        for (int i = 0; i < 8; i++) {
            int n = nbase + i;
            uint2 u = *(const uint2*)((const char*)xl + n * 512 + ((qpt ^ (n & 31)) << 4) + half);
            float rv = raw_l[n];
            float x0 = bf2f(u.x & 0xFFFFu), x1 = bf2f(u.x >> 16);
            float x2 = bf2f(u.y & 0xFFFFu), x3 = bf2f(u.y >> 16);
            pp[0] = fmaf(x0, rv, pp[0]); tt[0] += x0;
            pp[1] = fmaf(x1, rv, pp[1]); tt[1] += x1;
            pp[2] = fmaf(x2, rv, pp[2]); tt[2] += x2;
            pp[3] = fmaf(x3, rv, pp[3]); tt[3] += x3;
        }

        // ---- convert + write next tile into the other buffer ----
        if (it < TILES - 1) {
            #pragma unroll
            for (int r = 0; r < 4; r++) {
                uint4 pk;
                pk.x = f2bf(v[0][r]) | (f2bf(v[1][r]) << 16);
                pk.y = f2bf(v[2][r]) | (f2bf(v[3][r]) << 16);
                pk.z = f2bf(v[4][r]) | (f2bf(v[5][r]) << 16);
                pk.w = f2bf(v[6][r]) | (f2bf(v[7][r]) << 16);
                int n = n4 + r;
                *(uint4*)&xw[n * 128 + ((qc ^ (n & 31)) << 2)] = pk;
            }
        }
        __syncthreads();
    }

    // ---- block-level P/T reduce (scratch = buf0; tile 7 read buf1) ----
    {
        float* red = (float*)xT;                 // [8 waves][512]: [0..255]=P, [256..511]=T
        float4_* pr = (float4_*)(red + w * 512);
        float4_* tr = (float4_*)(red + w * 512 + 256);
        pr[lane] = (float4_){pp[0], pp[1], pp[2], pp[3]};
        tr[lane] = (float4_){tt[0], tt[1], tt[2], tt[3]};
        __syncthreads();
        int sel = t >> 8, cc = t & 255;          // 256 thr P, 256 thr T
        float s = 0.f;
        #pragma unroll
        for (int g = 0; g < 8; g++)
            s += red[g * 512 + sel * 256 + cc];
        atomicAdd((sel ? T : P) + b * 256 + cc, s);
    }
}

// Kernel 2: per batch: min/sum over raw, write att output and pooled out
__global__ __launch_bounds__(256) void finalize_kernel(
    const float* __restrict__ raw, const float* __restrict__ P,
    const float* __restrict__ T, float* __restrict__ out)
{
    int b = blockIdx.x, t = threadIdx.x;
    const float* r = raw + (size_t)b * HW_;
    float v[16];
    float mn = 3.4e38f, sm = 0.f;
    #pragma unroll
    for (int i = 0; i < 16; i++) {
        v[i] = r[t + 256 * i];
        mn = fminf(mn, v[i]);
        sm += v[i];
    }
    #pragma unroll
    for (int off = 1; off < 64; off <<= 1) {
        mn = fminf(mn, __shfl_xor(mn, off, 64));
        sm += __shfl_xor(sm, off, 64);
    }
    __shared__ float smn[4], ssm[4];
    int w = t >> 6;
    if ((t & 63) == 0) { smn[w] = mn; ssm[w] = sm; }
    __syncthreads();
    mn = fminf(fminf(smn[0], smn[1]), fminf(smn[2], smn[3]));
    sm = (ssm[0] + ssm[1]) + (ssm[2] + ssm[3]);
    float S = sm - 4096.f * mn;                 // sum of (raw - min)
    float inv = 1.f / S;

    float* att = out + B_ * CIN + (size_t)b * HW_;
    #pragma unroll
    for (int i = 0; i < 16; i++) att[t + 256 * i] = (v[i] - mn) * inv;

    int ic = b * 256 + t;
    out[ic] = (P[ic] - mn * T[ic]) * inv;
}

extern "C" void kernel_launch(void* const* d_in, const int* in_sizes, int n_in,
                              void* d_out, int out_size, void* d_ws, size_t ws_size,
                              hipStream_t stream)
{
    const float* x   = (const float*)d_in[0];
    const float* g   = (const float*)d_in[1];
    const float* Wg  = (const float*)d_in[2];
    const float* bg  = (const float*)d_in[3];
    const float* Wx  = (const float*)d_in[4];
    const float* bx  = (const float*)d_in[5];
    const float* Wf  = (const float*)d_in[6];
    const float* bf  = (const float*)d_in[7];
    float* out = (float*)d_out;

    char* wsb = (char*)d_ws;
    uint4* WxR  = (uint4*)wsb;                            // 128 KB
    float* ggbx = (float*)(wsb + 131072);                 // 32 KB
    float* P    = ggbx + 8192;                            // 32 KB
    float* T    = P + 8192;                               // 32 KB
    float* raw  = T + 8192;                               // 512 KB

    prep_kernel<<<64, 256, 0, stream>>>(g, Wg, bg, Wx, bx, WxR, ggbx, P, T);
    attn_main<<<256, 512, 0, stream>>>(x, (const char*)WxR, ggbx, Wf, bf, P, T, raw);
    finalize_kernel<<<32, 256, 0, stream>>>(raw, P, T, out);
}

// Round 3
// 231.560 us; speedup vs baseline: 1.0933x; 1.0042x over previous
//
#include <hip/hip_runtime.h>
#include <stdint.h>

#define B_   32
#define CIN  256
#define COUT 512
#define A_   256
#define HW_  4096
#define NT   64
#define TILES 8

typedef short  short8  __attribute__((ext_vector_type(8)));
typedef float  float4_ __attribute__((ext_vector_type(4)));

__device__ __forceinline__ unsigned f2bf(float f) {
    unsigned u = __float_as_uint(f);
    u += 0x7FFFu + ((u >> 16) & 1u);   // RNE to bf16
    return u >> 16;
}
__device__ __forceinline__ float bf2f(unsigned h) {
    return __uint_as_float(h << 16);
}

// Kernel 0 (grid 64):
//  blocks 0..31  : zero P/T, ggbx[b][a] = g@Wg.T + bg + bx
//  blocks 32..63 : WxR fragment-linear repack of Wx (bf16)
//    entry e = ((w8*8+kk)*4+ai)*64 + lane  holds Wx[a=w8*64+ai*16+(lane&15)]
//                                               [k=kk*32+(lane>>4)*8 .. +7]
__global__ __launch_bounds__(256) void prep_kernel(
    const float* __restrict__ g, const float* __restrict__ Wg,
    const float* __restrict__ bg, const float* __restrict__ Wx,
    const float* __restrict__ bx,
    uint4* __restrict__ WxR, float* __restrict__ ggbx,
    float* __restrict__ P, float* __restrict__ T)
{
    int t = threadIdx.x;
    if (blockIdx.x >= 32) {
        int e = (blockIdx.x - 32) * 256 + t;
        int lane = e & 63, ai = (e >> 6) & 3, kk = (e >> 8) & 7, w = e >> 11;
        int a  = w * 64 + ai * 16 + (lane & 15);
        int kb = kk * 32 + (lane >> 4) * 8;
        const float4* s = (const float4*)(Wx + (size_t)a * 256 + kb);
        float4 u0 = s[0], u1 = s[1];
        uint4 pk;
        pk.x = f2bf(u0.x) | (f2bf(u0.y) << 16);
        pk.y = f2bf(u0.z) | (f2bf(u0.w) << 16);
        pk.z = f2bf(u1.x) | (f2bf(u1.y) << 16);
        pk.w = f2bf(u1.z) | (f2bf(u1.w) << 16);
        WxR[e] = pk;
        return;
    }
    int b = blockIdx.x;
    int i = b * 256 + t;
    P[i] = 0.f; T[i] = 0.f;

    __shared__ float gl[COUT];
    gl[t]       = g[b * COUT + t];
    gl[t + 256] = g[b * COUT + 256 + t];
    __syncthreads();

    float acc0 = bg[t] + bx[t], acc1 = 0.f;    // a = t, dual chain for ILP
    const float4* wr = (const float4*)(Wg + (size_t)t * COUT);
    #pragma unroll 8
    for (int co = 0; co < COUT / 4; co += 2) {
        float4 wv0 = wr[co],     gv0 = *(const float4*)&gl[co * 4];
        float4 wv1 = wr[co + 1], gv1 = *(const float4*)&gl[co * 4 + 4];
        acc0 += wv0.x * gv0.x + wv0.y * gv0.y + wv0.z * gv0.z + wv0.w * gv0.w;
        acc1 += wv1.x * gv1.x + wv1.y * gv1.y + wv1.z * gv1.z + wv1.w * gv1.w;
    }
    ggbx[b * 256 + t] = acc0 + acc1;
}

// Kernel 1: grid 256 (1 block/CU), 512 threads (8 waves). Each block owns
// (b, tg) = 8 consecutive n-tiles of 64. Pipeline per tile:
//   issue loads(i+1) [pinned early] -> GEMM/epilogue/PT on buf[i&1]
//   -> convert+write buf[(i+1)&1]
// Wave w owns a in [w*32, w*32+32). SWAPPED MFMA operands: D[a][n] =
// mfma(Wx_frag, x_frag) so the reduce-over-a axis is (quad, reg) = in-lane
// + 2 shuffles, instead of 64 cross-lane shuffles per thread per tile.
__global__ __launch_bounds__(512)
__attribute__((amdgpu_waves_per_eu(2, 2)))
void attn_main(
    const float* __restrict__ x, const char* __restrict__ WxR,
    const float* __restrict__ ggbx, const float* __restrict__ Wf,
    const float* __restrict__ bfs,
    float* __restrict__ P, float* __restrict__ T, float* __restrict__ raw)
{
    // xT[buf][n][chunk]: chunk q (8 c as bf16x8) XOR-swizzled by n&31
    __shared__ unsigned int xT[2][NT * 128];    // 2 x 32 KB
    __shared__ float att_part[8][NT];
    __shared__ float raw_l[NT];

    int bid = blockIdx.x;
    int b = bid >> 3, tg = bid & 7;
    int t = threadIdx.x, w = t >> 6, lane = t & 63;
    int quad = lane >> 4, l15 = lane & 15;

    const float* xb = x + (size_t)b * CIN * HW_ + tg * (TILES * NT);

    // ---- persistent A fragments (Wx): wave w -> a in [w*32, w*32+32) ----
    short8 bfp[16];
    {
        const char* wsl = WxR + (w >> 1) * 32768 + (w & 1) * 2048 + lane * 16;
        #pragma unroll
        for (int kk = 0; kk < 8; kk++) {
            bfp[kk * 2]     = *(const short8*)(wsl + kk * 4096);
            bfp[kk * 2 + 1] = *(const short8*)(wsl + kk * 4096 + 1024);
        }
    }

    // per-lane gg+bx and Wf for a = w*32 + ai*16 + quad*4 + r  (r=0..3)
    float4_ ga4[2], wf4[2];
    #pragma unroll
    for (int ai = 0; ai < 2; ai++) {
        int a0 = w * 32 + ai * 16 + quad * 4;
        ga4[ai] = *(const float4_*)&ggbx[b * 256 + a0];
        wf4[ai] = *(const float4_*)&Wf[a0];
    }

    // staging geometry: wave w stages c in [w*32, w*32+32), 8 rows/thread
    int n4 = l15 * 4;
    int cb = w * 32 + quad * 8;
    int qc = cb >> 3;                            // = w*4 + quad
    const float* xrow = xb + (size_t)cb * HW_ + n4;

    // ---- prologue: tile 0 ----
    float4_ v[8];
    #pragma unroll
    for (int j = 0; j < 8; j++)
        v[j] = *(const float4_*)(xrow + (size_t)j * HW_);
    #pragma unroll
    for (int r = 0; r < 4; r++) {
        uint4 pk;
        pk.x = f2bf(v[0][r]) | (f2bf(v[1][r]) << 16);
        pk.y = f2bf(v[2][r]) | (f2bf(v[3][r]) << 16);
        pk.z = f2bf(v[4][r]) | (f2bf(v[5][r]) << 16);
        pk.w = f2bf(v[6][r]) | (f2bf(v[7][r]) << 16);
        int n = n4 + r;
        *(uint4*)&xT[0][n * 128 + ((qc ^ (n & 31)) << 2)] = pk;
    }

    float pp[4] = {0.f, 0.f, 0.f, 0.f};
    float tt[4] = {0.f, 0.f, 0.f, 0.f};
    int qpt   = (t & 63) >> 1;                   // P/T: logical chunk (8 c)
    int half  = (t & 1) * 8;                     // which 4 c of the chunk
    int nbase = w * 8;                           // P/T: 8 n per wave

    __syncthreads();

    // unroll 1: keep one tile's register state live at a time
    #pragma unroll 1
    for (int it = 0; it < TILES; it++) {
        const unsigned int* xl = xT[it & 1];
        unsigned int* xw = xT[(it + 1) & 1];

        // issue next tile's loads; sched_barrier pins them here so they
        // land under GEMM+epilogue+P/T instead of sinking to the convert
        if (it < TILES - 1) {
            const float* xn = xrow + (it + 1) * NT;
            #pragma unroll
            for (int j = 0; j < 8; j++)
                v[j] = *(const float4_*)(xn + (size_t)j * HW_);
        }
        __builtin_amdgcn_sched_barrier(0);

        // ---- K loop: pure LDS + MFMA; D[a][n] = Wx_frag x x_frag ----
        float4_ acc[4][2];
        #pragma unroll
        for (int mi = 0; mi < 4; mi++) {
            acc[mi][0] = (float4_){0.f, 0.f, 0.f, 0.f};
            acc[mi][1] = (float4_){0.f, 0.f, 0.f, 0.f};
        }
        short8 afA[4], afB[4];
        auto LDA = [&](short8* af, int k0) {
            int qk = (k0 >> 3) + quad;
            #pragma unroll
            for (int mi = 0; mi < 4; mi++) {
                int n = mi * 16 + l15;
                af[mi] = *(const short8*)&xl[n * 128 + ((qk ^ (n & 31)) << 2)];
            }
        };
        auto MM = [&](short8* af, int ks) {
            #pragma unroll
            for (int mi = 0; mi < 4; mi++) {
                acc[mi][0] = __builtin_amdgcn_mfma_f32_16x16x32_bf16(
                    bfp[ks * 2],     af[mi], acc[mi][0], 0, 0, 0);
                acc[mi][1] = __builtin_amdgcn_mfma_f32_16x16x32_bf16(
                    bfp[ks * 2 + 1], af[mi], acc[mi][1], 0, 0, 0);
            }
        };

        LDA(afA, 0);   LDA(afB, 32);
        MM(afA, 0);    LDA(afA, 64);
        MM(afB, 1);    LDA(afB, 96);
        MM(afA, 2);    LDA(afA, 128);
        MM(afB, 3);    LDA(afB, 160);
        MM(afA, 4);    LDA(afA, 192);
        MM(afB, 5);    LDA(afB, 224);
        MM(afA, 6);
        MM(afB, 7);

        // ---- epilogue: relu(D + gg + bx) * Wf; a-reduce is in-lane over
        // (ai, r) + 2 cross-quad shuffles. acc[mi][ai][r] =
        // D[a = w*32+ai*16+quad*4+r][n = mi*16+l15]
        #pragma unroll
        for (int mi = 0; mi < 4; mi++) {
            float p = 0.f;
            #pragma unroll
            for (int ai = 0; ai < 2; ai++) {
                #pragma unroll
                for (int r = 0; r < 4; r++) {
                    float vv = fmaxf(acc[mi][ai][r] + ga4[ai][r], 0.f);
                    p = fmaf(vv, wf4[ai][r], p);
                }
            }
            p += __shfl_xor(p, 16, 64);
            p += __shfl_xor(p, 32, 64);
            if (quad == 0) att_part[w][mi * 16 + l15] = p;
        }
        __syncthreads();

        if (t < NT) {
            float rv = att_part[0][t] + att_part[1][t] + att_part[2][t] + att_part[3][t]
                     + att_part[4][t] + att_part[5][t] + att_part[6][t] + att_part[7][t]
                     + bfs[0];
            raw[b * HW_ + (tg * TILES + it) * NT + t] = rv;
            raw_l[t] = rv;
        }
        __syncthreads();

        // ---- P/T accumulate: thread owns 4 c over 8 n, across all tiles ----
        #pragma unroll
        for (int i = 0; i < 8; i++) {
            int n = nbase + i;
            uint2 u = *(const uint2*)((const char*)xl + n * 512 + ((qpt ^ (n & 31)) << 4) + half);
            float rv = raw_l[n];
            float x0 = bf2f(u.x & 0xFFFFu), x1 = bf2f(u.x >> 16);
            float x2 = bf2f(u.y & 0xFFFFu), x3 = bf2f(u.y >> 16);
            pp[0] = fmaf(x0, rv, pp[0]); tt[0] += x0;
            pp[1] = fmaf(x1, rv, pp[1]); tt[1] += x1;
            pp[2] = fmaf(x2, rv, pp[2]); tt[2] += x2;
            pp[3] = fmaf(x3, rv, pp[3]); tt[3] += x3;
        }

        // ---- convert + write next tile into the other buffer ----
        if (it < TILES - 1) {
            #pragma unroll
            for (int r = 0; r < 4; r++) {
                uint4 pk;
                pk.x = f2bf(v[0][r]) | (f2bf(v[1][r]) << 16);
                pk.y = f2bf(v[2][r]) | (f2bf(v[3][r]) << 16);
                pk.z = f2bf(v[4][r]) | (f2bf(v[5][r]) << 16);
                pk.w = f2bf(v[6][r]) | (f2bf(v[7][r]) << 16);
                int n = n4 + r;
                *(uint4*)&xw[n * 128 + ((qc ^ (n & 31)) << 2)] = pk;
            }
        }
        __syncthreads();
    }

    // ---- block-level P/T reduce (scratch = buf0; tile 7 read buf1) ----
    {
        float* red = (float*)xT;                 // [8 waves][512]: [0..255]=P, [256..511]=T
        float4_* pr = (float4_*)(red + w * 512);
        float4_* tr = (float4_*)(red + w * 512 + 256);
        pr[lane] = (float4_){pp[0], pp[1], pp[2], pp[3]};
        tr[lane] = (float4_){tt[0], tt[1], tt[2], tt[3]};
        __syncthreads();
        int sel = t >> 8, cc = t & 255;          // 256 thr P, 256 thr T
        float s = 0.f;
        #pragma unroll
        for (int g = 0; g < 8; g++)
            s += red[g * 512 + sel * 256 + cc];
        atomicAdd((sel ? T : P) + b * 256 + cc, s);
    }
}

// Kernel 2: per batch: min/sum over raw, write att output and pooled out
__global__ __launch_bounds__(256) void finalize_kernel(
    const float* __restrict__ raw, const float* __restrict__ P,
    const float* __restrict__ T, float* __restrict__ out)
{
    int b = blockIdx.x, t = threadIdx.x;
    const float* r = raw + (size_t)b * HW_;
    float v[16];
    float mn = 3.4e38f, sm = 0.f;
    #pragma unroll
    for (int i = 0; i < 16; i++) {
        v[i] = r[t + 256 * i];
        mn = fminf(mn, v[i]);
        sm += v[i];
    }
    #pragma unroll
    for (int off = 1; off < 64; off <<= 1) {
        mn = fminf(mn, __shfl_xor(mn, off, 64));
        sm += __shfl_xor(sm, off, 64);
    }
    __shared__ float smn[4], ssm[4];
    int w = t >> 6;
    if ((t & 63) == 0) { smn[w] = mn; ssm[w] = sm; }
    __syncthreads();
    mn = fminf(fminf(smn[0], smn[1]), fminf(smn[2], smn[3]));
    sm = (ssm[0] + ssm[1]) + (ssm[2] + ssm[3]);
    float S = sm - 4096.f * mn;                 // sum of (raw - min)
    float inv = 1.f / S;

    float* att = out + B_ * CIN + (size_t)b * HW_;
    #pragma unroll
    for (int i = 0; i < 16; i++) att[t + 256 * i] = (v[i] - mn) * inv;

    int ic = b * 256 + t;
    out[ic] = (P[ic] - mn * T[ic]) * inv;
}

extern "C" void kernel_launch(void* const* d_in, const int* in_sizes, int n_in,
                              void* d_out, int out_size, void* d_ws, size_t ws_size,
                              hipStream_t stream)
{
    const float* x   = (const float*)d_in[0];
    const float* g   = (const float*)d_in[1];
    const float* Wg  = (const float*)d_in[2];
    const float* bg  = (const float*)d_in[3];
    const float* Wx  = (const float*)d_in[4];
    const float* bx  = (const float*)d_in[5];
    const float* Wf  = (const float*)d_in[6];
    const float* bf  = (const float*)d_in[7];
    float* out = (float*)d_out;

    char* wsb = (char*)d_ws;
    uint4* WxR  = (uint4*)wsb;                            // 128 KB
    float* ggbx = (float*)(wsb + 131072);                 // 32 KB
    float* P    = ggbx + 8192;                            // 32 KB
    float* T    = P + 8192;                               // 32 KB
    float* raw  = T + 8192;                               // 512 KB

    prep_kernel<<<64, 256, 0, stream>>>(g, Wg, bg, Wx, bx, WxR, ggbx, P, T);
    attn_main<<<256, 512, 0, stream>>>(x, (const char*)WxR, ggbx, Wf, bf, P, T, raw);
    finalize_kernel<<<32, 256, 0, stream>>>(raw, P, T, out);
}